// Round 1
// baseline (496.754 us; speedup 1.0000x reference)
//
#include <hip/hip_runtime.h>

// Conv2dSelfAttention: B=16, C=512, Cb=64, N=64*64=4096
// Pipeline: K0 W-prep (bf16 hi/lo) -> K1 QKV (bf16 MFMA, split hi/lo for q,k)
//   -> K2a partial logits (fp32) -> K2b reduce+softmax -> K2c M'=gamma*Wo@attn
//   -> K3 out = M'@V + gamma*b_o + x (fp32, fused residual)

#define NB  16
#define NC  512
#define NCB 64
#define NSP 4096
#define NM  192   // q(64)+k(64)+v(64) stacked rows

typedef __bf16 bf16x8 __attribute__((ext_vector_type(8)));
typedef unsigned short u16x8 __attribute__((ext_vector_type(8)));
typedef float f32x4 __attribute__((ext_vector_type(4)));

union F8 { bf16x8 bf; u16x8 us; };

__device__ __forceinline__ unsigned short f2bfu(float f) {
  unsigned u = __builtin_bit_cast(unsigned, f);
  unsigned r = u + 0x7fffu + ((u >> 16) & 1u);   // RNE
  return (unsigned short)(r >> 16);
}
__device__ __forceinline__ float bfu2f(unsigned short h) {
  return __builtin_bit_cast(float, ((unsigned)h) << 16);
}

// ---------------- K0: prepack weights to bf16 hi/lo ----------------
// Whi rows: [0,64) = wq, [64,128) = wk, [128,192) = wv. Wlo only q,k rows.
__global__ __launch_bounds__(256) void k0_wprep(
    const float* __restrict__ wq, const float* __restrict__ wk,
    const float* __restrict__ wv,
    unsigned short* __restrict__ Whi, unsigned short* __restrict__ Wlo) {
  int i = blockIdx.x * 256 + threadIdx.x;
  if (i < 2 * NCB * NC) {               // q,k: hi + lo
    const float* src = (i < NCB * NC) ? wq : wk;
    int j = (i < NCB * NC) ? i : i - NCB * NC;
    float f = src[j];
    unsigned short h = f2bfu(f);
    Whi[i] = h;
    Wlo[i] = f2bfu(f - bfu2f(h));
  } else if (i < 3 * NCB * NC) {        // v: hi only
    Whi[i] = f2bfu(wv[i - 2 * NCB * NC]);
  }
}

// ---------------- K1: QKV = Wqkv @ X_b, bf16 MFMA 16x16x32 ----------------
// Grid (64 n-tiles, 3 m-tiles(q/k/v), 16 b), 256 thr (4 waves).
// Output tile 64m x 64n; wave w owns rows 16w..16w+15, all 64 cols.
// q,k tiles: 3-term split bf16 (Ahi*Bhi + Ahi*Blo + Alo*Bhi). v: 1 term.
// LDS staged in MFMA fragment order -> all ds accesses are contiguous b128.
__global__ __launch_bounds__(256) void k1_qkv(
    const float* __restrict__ x,
    const unsigned short* __restrict__ Whi, const unsigned short* __restrict__ Wlo,
    const float* __restrict__ bq, const float* __restrict__ bk,
    const float* __restrict__ bv, float* __restrict__ qkv) {
  const int nt = blockIdx.x;
  const int mt = blockIdx.y;
  const int b  = blockIdx.z;
  const int t  = threadIdx.x;
  const int lane = t & 63;
  const int wid  = t >> 6;
  const bool split = (mt < 2);
  const float* bias = (mt == 0) ? bq : (mt == 1) ? bk : bv;

  __shared__ F8 ldsBhi[4][64], ldsBlo[4][64], ldsAhi[4][64], ldsAlo[4][64];

  const int f   = wid;          // fragment this thread stages
  const int q4  = lane >> 4;    // quad
  const int l16 = lane & 15;
  const int nloc  = f * 16 + l16;          // B: local col / A: local row
  const int n_g   = nt * 64 + nloc;        // global spatial col
  const int mrowA = mt * 64 + nloc;        // global weight row

  f32x4 acc[4] = {};
  const float* xb = x + (long)b * NC * NSP;

  for (int c0 = 0; c0 < NC; c0 += 32) {
    const int kbase = c0 + q4 * 8;
    // gather x fragment (8 scalars, stride NSP) + hi/lo convert
    F8 bhi, blo;
#pragma unroll
    for (int j = 0; j < 8; j++) {
      float v = xb[(long)(kbase + j) * NSP + n_g];
      unsigned short h = f2bfu(v);
      bhi.us[j] = h;
      if (split) blo.us[j] = f2bfu(v - bfu2f(h));
    }
    // weight fragment: contiguous 16B prepacked load
    F8 ahi, alo;
    ahi.us = *(const u16x8*)&Whi[(long)mrowA * NC + kbase];
    if (split) alo.us = *(const u16x8*)&Wlo[(long)(mrowA - 0) * NC + kbase - 0 - (mt == 0 ? 0 : 0)]; // see note below
    // NOTE: Wlo is indexed by q/k row only (rows 0..127 of Whi order):
    if (split) alo.us = *(const u16x8*)&Wlo[(long)mrowA * NC + kbase];

    __syncthreads();            // previous compute done reading LDS
    ldsBhi[f][lane] = bhi;
    ldsAhi[f][lane] = ahi;
    if (split) { ldsBlo[f][lane] = blo; ldsAlo[f][lane] = alo; }
    __syncthreads();

    F8 a_hi = ldsAhi[wid][lane];
    F8 a_lo; if (split) a_lo = ldsAlo[wid][lane];
#pragma unroll
    for (int nn = 0; nn < 4; nn++) {
      F8 b_hi = ldsBhi[nn][lane];
      acc[nn] = __builtin_amdgcn_mfma_f32_16x16x32_bf16(a_hi.bf, b_hi.bf, acc[nn], 0, 0, 0);
      if (split) {
        F8 b_lo = ldsBlo[nn][lane];
        acc[nn] = __builtin_amdgcn_mfma_f32_16x16x32_bf16(a_hi.bf, b_lo.bf, acc[nn], 0, 0, 0);
        acc[nn] = __builtin_amdgcn_mfma_f32_16x16x32_bf16(a_lo.bf, b_hi.bf, acc[nn], 0, 0, 0);
      }
    }
  }

  // epilogue: C/D layout col=lane&15, row=(lane>>4)*4+reg
  const int rowbase = wid * 16 + q4 * 4;
#pragma unroll
  for (int nn = 0; nn < 4; nn++) {
    int n = nt * 64 + nn * 16 + l16;
#pragma unroll
    for (int r = 0; r < 4; r++) {
      int mrow = rowbase + r;
      qkv[(long)(b * NM + mt * 64 + mrow) * NSP + n] = acc[nn][r] + bias[mrow];
    }
  }
}

// ---------------- K2a: partial logits, fp32 ----------------
// Grid (64 n-chunks of 64, 16 b). part[b][ch][c][d] = sum_{n in chunk} Q[c,n]K[d,n]
__global__ __launch_bounds__(256) void k2a_logits(const float* __restrict__ qkv,
                                                  float* __restrict__ part) {
  const int ch = blockIdx.x;
  const int b  = blockIdx.y;
  const int t  = threadIdx.x;
  __shared__ float ldsQ[64][68];    // [c][n]  (+4 pad: conflict-free)
  __shared__ float ldsKT[64][68];   // [n][d]  transposed for b128 reads
  const int n0 = ch * 64;
  const float* Qb = qkv + (long)(b * NM) * NSP;
  const float* Kb = Qb + (long)NCB * NSP;

  for (int i = t; i < 1024; i += 256) {
    int r = i >> 4, c4 = (i & 15) << 2;
    *(f32x4*)&ldsQ[r][c4] = *(const f32x4*)&Qb[(long)r * NSP + n0 + c4];
    f32x4 u = *(const f32x4*)&Kb[(long)r * NSP + n0 + c4];
    ldsKT[c4 + 0][r] = u[0]; ldsKT[c4 + 1][r] = u[1];
    ldsKT[c4 + 2][r] = u[2]; ldsKT[c4 + 3][r] = u[3];
  }
  __syncthreads();

  const int cc0 = (t >> 4) << 2, dd0 = (t & 15) << 2;
  float acc[4][4] = {};
  for (int n = 0; n < 64; n += 4) {
    f32x4 qv[4], kv[4];
#pragma unroll
    for (int i = 0; i < 4; i++) qv[i] = *(const f32x4*)&ldsQ[cc0 + i][n];
#pragma unroll
    for (int p = 0; p < 4; p++) kv[p] = *(const f32x4*)&ldsKT[n + p][dd0];
#pragma unroll
    for (int i = 0; i < 4; i++)
#pragma unroll
      for (int p = 0; p < 4; p++) {
        float qq = qv[i][p];
        acc[i][0] += qq * kv[p][0]; acc[i][1] += qq * kv[p][1];
        acc[i][2] += qq * kv[p][2]; acc[i][3] += qq * kv[p][3];
      }
  }
  float* dst = part + (long)(b * 64 + ch) * 4096;
#pragma unroll
  for (int i = 0; i < 4; i++)
#pragma unroll
    for (int j = 0; j < 4; j++)
      dst[(cc0 + i) * 64 + dd0 + j] = acc[i][j];
}

// ---------------- K2b: reduce partials + row softmax ----------------
__global__ __launch_bounds__(256) void k2b_softmax(const float* __restrict__ part,
                                                   float* __restrict__ attn) {
  const int b = blockIdx.x;
  const int t = threadIdx.x;
  __shared__ float lg[64][65];
  for (int e = t; e < 4096; e += 256) {
    float s = 0.f;
    const float* p = part + (long)b * 64 * 4096 + e;
#pragma unroll 8
    for (int c = 0; c < 64; c++) s += p[c * 4096];
    lg[e >> 6][e & 63] = s;
  }
  __syncthreads();
  if (t < 64) {
    float mx = -1e30f;
    for (int d = 0; d < 64; d++) mx = fmaxf(mx, lg[t][d]);
    float sum = 0.f;
    for (int d = 0; d < 64; d++) { float e = __expf(lg[t][d] - mx); lg[t][d] = e; sum += e; }
    float inv = 1.f / sum;
    for (int d = 0; d < 64; d++) attn[(long)(b * 64 + t) * 64 + d] = lg[t][d] * inv;
  }
}

// ---------------- K2c: M' = gamma * Wo @ attn  [512x64 per batch] ----------------
__global__ __launch_bounds__(256) void k2c_mprime(const float* __restrict__ attn,
    const float* __restrict__ wo, const float* __restrict__ gamma,
    float* __restrict__ Mp) {
  const int cb = blockIdx.x;   // 8 c-blocks of 64
  const int b  = blockIdx.y;
  const int t  = threadIdx.x;
  __shared__ float ldsW[64][68];  // [ci][e]
  __shared__ float ldsA[64][68];  // [e][d]
  for (int i = t; i < 1024; i += 256) {
    int r = i >> 4, c4 = (i & 15) << 2;
    *(f32x4*)&ldsW[r][c4] = *(const f32x4*)&wo[(long)(cb * 64 + r) * 64 + c4];
    *(f32x4*)&ldsA[r][c4] = *(const f32x4*)&attn[(long)(b * 64 + r) * 64 + c4];
  }
  __syncthreads();
  const int cc0 = (t >> 4) << 2, dd0 = (t & 15) << 2;
  float acc[4][4] = {};
  for (int e = 0; e < 64; e += 4) {
    f32x4 wv4[4], av[4];
#pragma unroll
    for (int i = 0; i < 4; i++) wv4[i] = *(const f32x4*)&ldsW[cc0 + i][e];
#pragma unroll
    for (int p = 0; p < 4; p++) av[p] = *(const f32x4*)&ldsA[e + p][dd0];
#pragma unroll
    for (int i = 0; i < 4; i++)
#pragma unroll
      for (int p = 0; p < 4; p++) {
        float ww = wv4[i][p];
        acc[i][0] += ww * av[p][0]; acc[i][1] += ww * av[p][1];
        acc[i][2] += ww * av[p][2]; acc[i][3] += ww * av[p][3];
      }
  }
  const float g = gamma[0];
  float* dst = Mp + (long)(b * NC + cb * 64) * 64;
#pragma unroll
  for (int i = 0; i < 4; i++)
#pragma unroll
    for (int j = 0; j < 4; j++)
      dst[(cc0 + i) * 64 + dd0 + j] = g * acc[i][j];
}

// ---------------- K3: out = M' @ V + gamma*b_o + x  (fp32, HBM-bound) ----------------
// Grid (64 n-tiles, 8 c-tiles, 16 b), tile 64c x 64n, K=64.
__global__ __launch_bounds__(256) void k3_out(const float* __restrict__ qkv,
    const float* __restrict__ Mp, const float* __restrict__ x,
    const float* __restrict__ bo, const float* __restrict__ gamma,
    float* __restrict__ out) {
  const int ntb = blockIdx.x;
  const int cb  = blockIdx.y;
  const int b   = blockIdx.z;
  const int t   = threadIdx.x;
  __shared__ float ldsV[64][64];  // [d][n] (stride 64 ok: reads are row-contig)
  __shared__ float ldsM[64][68];  // [ci][d]
  const int n0 = ntb * 64, c0 = cb * 64;
  const float* Vb = qkv + (long)(b * NM + 128) * NSP;
  for (int i = t; i < 1024; i += 256) {
    int r = i >> 4, c4 = (i & 15) << 2;
    *(f32x4*)&ldsV[r][c4] = *(const f32x4*)&Vb[(long)r * NSP + n0 + c4];
    *(f32x4*)&ldsM[r][c4] = *(const f32x4*)&Mp[(long)(b * NC + c0 + r) * 64 + c4];
  }
  __syncthreads();
  const int cc0 = (t >> 4) << 2;
  const int nf4 = (t & 15) << 2;
  f32x4 acc[4] = {};
  for (int d = 0; d < 64; d += 4) {
    f32x4 m[4], v[4];
#pragma unroll
    for (int i = 0; i < 4; i++) m[i] = *(const f32x4*)&ldsM[cc0 + i][d];
#pragma unroll
    for (int p = 0; p < 4; p++) v[p] = *(const f32x4*)&ldsV[d + p][nf4];
#pragma unroll
    for (int i = 0; i < 4; i++)
#pragma unroll
      for (int p = 0; p < 4; p++) acc[i] += m[i][p] * v[p];
  }
  const float g = gamma[0];
#pragma unroll
  for (int i = 0; i < 4; i++) {
    int c = c0 + cc0 + i;
    f32x4 xr = *(const f32x4*)&x[(long)(b * NC + c) * NSP + n0 + nf4];
    float bb = g * bo[c];
    f32x4 o = acc[i] + xr + bb;
    *(f32x4*)&out[(long)(b * NC + c) * NSP + n0 + nf4] = o;
  }
}

extern "C" void kernel_launch(void* const* d_in, const int* in_sizes, int n_in,
                              void* d_out, int out_size, void* d_ws, size_t ws_size,
                              hipStream_t stream) {
  const float* x   = (const float*)d_in[0];
  const float* wq  = (const float*)d_in[1];
  const float* bq  = (const float*)d_in[2];
  const float* wk  = (const float*)d_in[3];
  const float* bk  = (const float*)d_in[4];
  const float* wv  = (const float*)d_in[5];
  const float* bv  = (const float*)d_in[6];
  const float* wo  = (const float*)d_in[7];
  const float* bo  = (const float*)d_in[8];
  const float* gm  = (const float*)d_in[9];
  float* out = (float*)d_out;
  float* ws  = (float*)d_ws;

  // workspace carve (floats): qkv 12.58M | part 4.19M | attn 64K | Mp 512K | Whi/Wlo
  float* qkv  = ws;
  float* part = ws + 12582912;
  float* attn = ws + 16777216;
  float* Mp   = ws + 16842752;
  unsigned short* Whi = (unsigned short*)(ws + 17367040);           // 192*512 u16
  unsigned short* Wlo = (unsigned short*)(ws + 17367040 + 49152);   // 128*512 u16

  k0_wprep<<<384, 256, 0, stream>>>(wq, wk, wv, Whi, Wlo);
  k1_qkv<<<dim3(64, 3, 16), 256, 0, stream>>>(x, Whi, Wlo, bq, bk, bv, qkv);
  k2a_logits<<<dim3(64, 16), 256, 0, stream>>>(qkv, part);
  k2b_softmax<<<16, 256, 0, stream>>>(part, attn);
  k2c_mprime<<<dim3(8, 16), 256, 0, stream>>>(attn, wo, gm, Mp);
  k3_out<<<dim3(64, 8, 16), 256, 0, stream>>>(qkv, Mp, x, bo, gm, out);
}

// Round 2
// 412.263 us; speedup vs baseline: 1.2049x; 1.2049x over previous
//
#include <hip/hip_runtime.h>

// Conv2dSelfAttention: B=16, C=512, Cb=64, N=64*64=4096
// K0 W-prep (bf16 hi/lo + fused bias) -> K1 QKV (barrier-free MFMA, x read once)
// -> K2a partial logits -> K2b reduce+softmax -> K2c M'=gamma*Wo@attn
// -> K3 out = M'@V + gamma*b_o + x (fp32, 128x128 tile)

#define NB  16
#define NC  512
#define NCB 64
#define NSP 4096
#define NM  192

typedef __bf16 bf16x8 __attribute__((ext_vector_type(8)));
typedef unsigned short u16x8 __attribute__((ext_vector_type(8)));
typedef float f32x4 __attribute__((ext_vector_type(4)));

union F8 { bf16x8 bf; u16x8 us; };

__device__ __forceinline__ unsigned short f2bfu(float f) {
  unsigned u = __builtin_bit_cast(unsigned, f);
  unsigned r = u + 0x7fffu + ((u >> 16) & 1u);   // RNE
  return (unsigned short)(r >> 16);
}
__device__ __forceinline__ float bfu2f(unsigned short h) {
  return __builtin_bit_cast(float, ((unsigned)h) << 16);
}

// ---------------- K0: prepack weights to bf16 hi/lo + bias concat ----------------
__global__ __launch_bounds__(256) void k0_wprep(
    const float* __restrict__ wq, const float* __restrict__ wk,
    const float* __restrict__ wv,
    const float* __restrict__ bq, const float* __restrict__ bk,
    const float* __restrict__ bv,
    unsigned short* __restrict__ Whi, unsigned short* __restrict__ Wlo,
    float* __restrict__ biasAll) {
  int i = blockIdx.x * 256 + threadIdx.x;
  if (i < 2 * NCB * NC) {               // q,k: hi + lo
    const float* src = (i < NCB * NC) ? wq : wk;
    int j = (i < NCB * NC) ? i : i - NCB * NC;
    float f = src[j];
    unsigned short h = f2bfu(f);
    Whi[i] = h;
    Wlo[i] = f2bfu(f - bfu2f(h));
  } else if (i < 3 * NCB * NC) {        // v: hi only
    Whi[i] = f2bfu(wv[i - 2 * NCB * NC]);
  }
  if (i < 192) {
    biasAll[i] = (i < 64) ? bq[i] : (i < 128) ? bk[i - 64] : bv[i - 128];
  }
}

// ---------------- K1: QKV = Wqkv @ X_b ----------------
// Grid (32 nt, 16 b), 512 thr (8 waves). Block tile: 192m x 128n, K=512.
// Wave (mh, nq): m-tiles mh*6..+5, n-tiles nq*2..+1. No LDS, no barriers:
// A-frags: contiguous 16B from prepacked Whi/Wlo (L1-hot).
// B-frags: per-wave scalar gather of x (each element read by 2 waves, L1/L2-hot).
__global__ __launch_bounds__(512, 4) void k1_qkv(
    const float* __restrict__ x,
    const unsigned short* __restrict__ Whi, const unsigned short* __restrict__ Wlo,
    const float* __restrict__ biasAll, float* __restrict__ qkv) {
  const int nt = blockIdx.x;
  const int b  = blockIdx.y;
  const int t  = threadIdx.x;
  const int lane = t & 63;
  const int wid  = t >> 6;
  const int mh = wid >> 2;       // 0,1
  const int nq = wid & 3;        // 0..3
  const int q4 = lane >> 4;
  const int l16 = lane & 15;
  const int n0 = nt * 128;

  const float* xb = x + (long)b * NC * NSP;
  f32x4 acc[12] = {};   // [ml*2 + ni]

  for (int c0 = 0; c0 < NC; c0 += 32) {
    const int kb = c0 + q4 * 8;
    F8 Bhi[2], Blo[2];
#pragma unroll
    for (int ni = 0; ni < 2; ni++) {
      const int n_g = n0 + (nq * 2 + ni) * 16 + l16;
      const float* src = xb + (long)kb * NSP + n_g;
#pragma unroll
      for (int j = 0; j < 8; j++) {
        float v = src[(long)j * NSP];
        unsigned short h = f2bfu(v);
        Bhi[ni].us[j] = h;
        Blo[ni].us[j] = f2bfu(v - bfu2f(h));
      }
    }
#pragma unroll
    for (int ml = 0; ml < 6; ml++) {
      const int mt = mh * 6 + ml;
      const bool sp = (mt < 8);          // q,k rows need split; compile-time per ml
      F8 Ahi, Alo;
      Ahi.us = *(const u16x8*)&Whi[(long)(mt * 16 + l16) * NC + kb];
      if (sp) Alo.us = *(const u16x8*)&Wlo[(long)(mt * 16 + l16) * NC + kb];
#pragma unroll
      for (int ni = 0; ni < 2; ni++) {
        acc[ml * 2 + ni] = __builtin_amdgcn_mfma_f32_16x16x32_bf16(
            Ahi.bf, Bhi[ni].bf, acc[ml * 2 + ni], 0, 0, 0);
        if (sp) {
          acc[ml * 2 + ni] = __builtin_amdgcn_mfma_f32_16x16x32_bf16(
              Ahi.bf, Blo[ni].bf, acc[ml * 2 + ni], 0, 0, 0);
          acc[ml * 2 + ni] = __builtin_amdgcn_mfma_f32_16x16x32_bf16(
              Alo.bf, Bhi[ni].bf, acc[ml * 2 + ni], 0, 0, 0);
        }
      }
    }
  }

  // epilogue: C/D layout col=lane&15, row=(lane>>4)*4+reg
#pragma unroll
  for (int ml = 0; ml < 6; ml++) {
    const int mt = mh * 6 + ml;
#pragma unroll
    for (int ni = 0; ni < 2; ni++) {
      const int n = n0 + (nq * 2 + ni) * 16 + l16;
#pragma unroll
      for (int r = 0; r < 4; r++) {
        const int mrow = mt * 16 + q4 * 4 + r;
        qkv[(long)(b * NM + mrow) * NSP + n] = acc[ml * 2 + ni][r] + biasAll[mrow];
      }
    }
  }
}

// ---------------- K2a: partial logits, fp32. Grid (8 ch, 16 b) ----------------
__global__ __launch_bounds__(256) void k2a_logits(const float* __restrict__ qkv,
                                                  float* __restrict__ part) {
  const int ch = blockIdx.x;   // 0..7, each covers 512 spatial
  const int b  = blockIdx.y;
  const int t  = threadIdx.x;
  __shared__ float ldsQ[64][68];
  __shared__ float ldsKT[64][68];
  const float* Qb = qkv + (long)(b * NM) * NSP;
  const float* Kb = Qb + (long)NCB * NSP;
  const int cc0 = (t >> 4) << 2, dd0 = (t & 15) << 2;
  float acc[4][4] = {};

  for (int s = 0; s < 8; s++) {
    const int n0 = ch * 512 + s * 64;
    __syncthreads();
    for (int i = t; i < 1024; i += 256) {
      int r = i >> 4, c4 = (i & 15) << 2;
      *(f32x4*)&ldsQ[r][c4] = *(const f32x4*)&Qb[(long)r * NSP + n0 + c4];
      f32x4 u = *(const f32x4*)&Kb[(long)r * NSP + n0 + c4];
      ldsKT[c4 + 0][r] = u[0]; ldsKT[c4 + 1][r] = u[1];
      ldsKT[c4 + 2][r] = u[2]; ldsKT[c4 + 3][r] = u[3];
    }
    __syncthreads();
    for (int n = 0; n < 64; n += 4) {
      f32x4 qv[4], kv[4];
#pragma unroll
      for (int i = 0; i < 4; i++) qv[i] = *(const f32x4*)&ldsQ[cc0 + i][n];
#pragma unroll
      for (int p = 0; p < 4; p++) kv[p] = *(const f32x4*)&ldsKT[n + p][dd0];
#pragma unroll
      for (int i = 0; i < 4; i++)
#pragma unroll
        for (int p = 0; p < 4; p++) {
          float qq = qv[i][p];
          acc[i][0] += qq * kv[p][0]; acc[i][1] += qq * kv[p][1];
          acc[i][2] += qq * kv[p][2]; acc[i][3] += qq * kv[p][3];
        }
    }
  }
  float* dst = part + (long)(b * 8 + ch) * 4096;
#pragma unroll
  for (int i = 0; i < 4; i++)
#pragma unroll
    for (int j = 0; j < 4; j++)
      dst[(cc0 + i) * 64 + dd0 + j] = acc[i][j];
}

// ---------------- K2b: reduce 8 partials + row softmax ----------------
__global__ __launch_bounds__(256) void k2b_softmax(const float* __restrict__ part,
                                                   float* __restrict__ attn) {
  const int b = blockIdx.x;
  const int t = threadIdx.x;
  __shared__ float lg[64][65];
  for (int e = t; e < 4096; e += 256) {
    float s = 0.f;
    const float* p = part + (long)b * 8 * 4096 + e;
#pragma unroll
    for (int c = 0; c < 8; c++) s += p[c * 4096];
    lg[e >> 6][e & 63] = s;
  }
  __syncthreads();
  if (t < 64) {
    float mx = -1e30f;
    for (int d = 0; d < 64; d++) mx = fmaxf(mx, lg[t][d]);
    float sum = 0.f;
    for (int d = 0; d < 64; d++) { float e = __expf(lg[t][d] - mx); lg[t][d] = e; sum += e; }
    float inv = 1.f / sum;
    for (int d = 0; d < 64; d++) attn[(long)(b * 64 + t) * 64 + d] = lg[t][d] * inv;
  }
}

// ---------------- K2c: M' = gamma * Wo @ attn ----------------
__global__ __launch_bounds__(256) void k2c_mprime(const float* __restrict__ attn,
    const float* __restrict__ wo, const float* __restrict__ gamma,
    float* __restrict__ Mp) {
  const int cb = blockIdx.x;
  const int b  = blockIdx.y;
  const int t  = threadIdx.x;
  __shared__ float ldsW[64][68];
  __shared__ float ldsA[64][68];
  for (int i = t; i < 1024; i += 256) {
    int r = i >> 4, c4 = (i & 15) << 2;
    *(f32x4*)&ldsW[r][c4] = *(const f32x4*)&wo[(long)(cb * 64 + r) * 64 + c4];
    *(f32x4*)&ldsA[r][c4] = *(const f32x4*)&attn[(long)(b * 64 + r) * 64 + c4];
  }
  __syncthreads();
  const int cc0 = (t >> 4) << 2, dd0 = (t & 15) << 2;
  float acc[4][4] = {};
  for (int e = 0; e < 64; e += 4) {
    f32x4 wv4[4], av[4];
#pragma unroll
    for (int i = 0; i < 4; i++) wv4[i] = *(const f32x4*)&ldsW[cc0 + i][e];
#pragma unroll
    for (int p = 0; p < 4; p++) av[p] = *(const f32x4*)&ldsA[e + p][dd0];
#pragma unroll
    for (int i = 0; i < 4; i++)
#pragma unroll
      for (int p = 0; p < 4; p++) {
        float ww = wv4[i][p];
        acc[i][0] += ww * av[p][0]; acc[i][1] += ww * av[p][1];
        acc[i][2] += ww * av[p][2]; acc[i][3] += ww * av[p][3];
      }
  }
  const float g = gamma[0];
  float* dst = Mp + (long)(b * NC + cb * 64) * 64;
#pragma unroll
  for (int i = 0; i < 4; i++)
#pragma unroll
    for (int j = 0; j < 4; j++)
      dst[(cc0 + i) * 64 + dd0 + j] = g * acc[i][j];
}

// ---------------- K3: out = M' @ V + gamma*b_o + x ----------------
// Grid (32 nt, 4 ct, 16 b). Tile 128c x 128n, K=64. Thread: 8c (stride 16) x 8n.
// ldsM pad 68 + c-stride-16 rows -> conflict-free f32x4 m-reads. V in 32-row halves.
__global__ __launch_bounds__(256, 3) void k3_out(const float* __restrict__ qkv,
    const float* __restrict__ Mp, const float* __restrict__ x,
    const float* __restrict__ bo, const float* __restrict__ gamma,
    float* __restrict__ out) {
  const int nt = blockIdx.x;
  const int ct = blockIdx.y;
  const int b  = blockIdx.z;
  const int t  = threadIdx.x;
  const int n0 = nt * 128, c0 = ct * 128;
  __shared__ float ldsM[128][68];
  __shared__ float ldsV[32][128];
  const float* Vb = qkv + (long)(b * NM + 128) * NSP;

  // stage M' tile [128c x 64d] once
  for (int k = 0; k < 8; k++) {
    int idx = k * 256 + t;
    int c = idx >> 4, dv = idx & 15;
    *(f32x4*)&ldsM[c][dv * 4] = *(const f32x4*)&Mp[(long)(b * NC + c0 + c) * 64 + dv * 4];
  }

  const int ci = t >> 4, ni = t & 15;
  f32x4 acc[8][2] = {};

  for (int vh = 0; vh < 2; vh++) {
    __syncthreads();    // first: also covers ldsM staging; later: protect restage
    for (int k = 0; k < 4; k++) {
      int idx = k * 256 + t;
      int row = idx >> 5, nv = idx & 31;
      *(f32x4*)&ldsV[row][nv * 4] =
          *(const f32x4*)&Vb[(long)(vh * 32 + row) * NSP + n0 + nv * 4];
    }
    __syncthreads();
    for (int dd = 0; dd < 32; dd += 4) {
      const int d = vh * 32 + dd;
      f32x4 mi[8];
#pragma unroll
      for (int i = 0; i < 8; i++) mi[i] = *(const f32x4*)&ldsM[ci + 16 * i][d];
#pragma unroll
      for (int p = 0; p < 4; p++) {
        f32x4 v0 = *(const f32x4*)&ldsV[dd + p][ni * 4];
        f32x4 v1 = *(const f32x4*)&ldsV[dd + p][ni * 4 + 64];
#pragma unroll
        for (int i = 0; i < 8; i++) {
          acc[i][0] += mi[i][p] * v0;
          acc[i][1] += mi[i][p] * v1;
        }
      }
    }
  }

  const float g = gamma[0];
#pragma unroll
  for (int i = 0; i < 8; i++) {
    const int c = c0 + ci + 16 * i;
    const float bb = g * bo[c];
#pragma unroll
    for (int h = 0; h < 2; h++) {
      long off = (long)(b * NC + c) * NSP + n0 + ni * 4 + h * 64;
      f32x4 xr = *(const f32x4*)&x[off];
      f32x4 o = acc[i][h] + xr + bb;
      *(f32x4*)&out[off] = o;
    }
  }
}

extern "C" void kernel_launch(void* const* d_in, const int* in_sizes, int n_in,
                              void* d_out, int out_size, void* d_ws, size_t ws_size,
                              hipStream_t stream) {
  const float* x   = (const float*)d_in[0];
  const float* wq  = (const float*)d_in[1];
  const float* bq  = (const float*)d_in[2];
  const float* wk  = (const float*)d_in[3];
  const float* bk  = (const float*)d_in[4];
  const float* wv  = (const float*)d_in[5];
  const float* bv  = (const float*)d_in[6];
  const float* wo  = (const float*)d_in[7];
  const float* bo  = (const float*)d_in[8];
  const float* gm  = (const float*)d_in[9];
  float* out = (float*)d_out;
  float* ws  = (float*)d_ws;

  // ws carve (floats)
  float* qkv  = ws;                       // 192*4096*16 = 12,582,912
  float* part = ws + 12582912;            // 8*16*4096   = 524,288
  float* attn = ws + 13107200;            // 65,536
  float* Mp   = ws + 13172736;            // 524,288
  unsigned short* Whi = (unsigned short*)(ws + 13697024);   // 192*512 u16
  unsigned short* Wlo = (unsigned short*)(ws + 13746176);   // 128*512 u16
  float* biasAll = ws + 13778944;         // 192

  k0_wprep<<<384, 256, 0, stream>>>(wq, wk, wv, bq, bk, bv, Whi, Wlo, biasAll);
  k1_qkv<<<dim3(32, 16), 512, 0, stream>>>(x, Whi, Wlo, biasAll, qkv);
  k2a_logits<<<dim3(8, 16), 256, 0, stream>>>(qkv, part);
  k2b_softmax<<<16, 256, 0, stream>>>(part, attn);
  k2c_mprime<<<dim3(8, 16), 256, 0, stream>>>(attn, wo, gm, Mp);
  k3_out<<<dim3(32, 4, 16), 256, 0, stream>>>(qkv, Mp, x, bo, gm, out);
}

// Round 3
// 375.731 us; speedup vs baseline: 1.3221x; 1.0972x over previous
//
#include <hip/hip_runtime.h>

// Conv2dSelfAttention: B=16, C=512, Cb=64, N=64*64=4096
// K0 W-prep (bf16 hi/lo + bias concat)
// K1 QKV: block-staged LDS (fragment order, swizzled), dbuf 1-barrier, split-bf16 MFMA
// K2a partial logits -> K2b wave-per-row reduce+softmax -> K2c M'=gamma*Wo@attn
// K3 out = M'@V + gamma*b_o + x

#define NB  16
#define NC  512
#define NCB 64
#define NSP 4096
#define NM  192

typedef __bf16 bf16x8 __attribute__((ext_vector_type(8)));
typedef unsigned short u16x8 __attribute__((ext_vector_type(8)));
typedef float f32x4 __attribute__((ext_vector_type(4)));

union F8 { bf16x8 bf; u16x8 us; };

__device__ __forceinline__ unsigned short f2bfu(float f) {
  unsigned u = __builtin_bit_cast(unsigned, f);
  unsigned r = u + 0x7fffu + ((u >> 16) & 1u);   // RNE
  return (unsigned short)(r >> 16);
}
__device__ __forceinline__ float bfu2f(unsigned short h) {
  return __builtin_bit_cast(float, ((unsigned)h) << 16);
}

// ---------------- K0: prepack weights to bf16 hi/lo + bias concat ----------------
__global__ __launch_bounds__(256) void k0_wprep(
    const float* __restrict__ wq, const float* __restrict__ wk,
    const float* __restrict__ wv,
    const float* __restrict__ bq, const float* __restrict__ bk,
    const float* __restrict__ bv,
    unsigned short* __restrict__ Whi, unsigned short* __restrict__ Wlo,
    float* __restrict__ biasAll) {
  int i = blockIdx.x * 256 + threadIdx.x;
  if (i < 2 * NCB * NC) {               // q,k: hi + lo
    const float* src = (i < NCB * NC) ? wq : wk;
    int j = (i < NCB * NC) ? i : i - NCB * NC;
    float f = src[j];
    unsigned short h = f2bfu(f);
    Whi[i] = h;
    Wlo[i] = f2bfu(f - bfu2f(h));
  } else if (i < 3 * NCB * NC) {        // v: hi only
    Whi[i] = f2bfu(wv[i - 2 * NCB * NC]);
  }
  if (i < 192) {
    biasAll[i] = (i < 64) ? bq[i] : (i < 128) ? bk[i - 64] : bv[i - 128];
  }
}

// ---------------- K1: QKV = Wqkv @ X_b ----------------
// Grid (32 nt, 16 b), 512 thr. Block tile 192m x 128n, K=512 in 16 steps of 32.
// Staging: thread (sn=t&127, skb=t>>7) loads 8 k-strided floats (n-coalesced 256B
// per wave instr), converts hi/lo, writes ONE b128 each to LDS fragment-order
// [n][kb^(n&3)] (store 2-way=free, frag read conflict-free). Double-buffered,
// one barrier per step, register prefetch of next step behind MFMA phase.
// Wave (mh,nq): 4 split m-tiles (mh*4..+3) x3 MFMA + 2 v m-tiles (8+mh*2..) x1
// = uniform 28 MFMA/wave/step.
__global__ __launch_bounds__(512, 4) void k1_qkv(
    const float* __restrict__ x,
    const unsigned short* __restrict__ Whi, const unsigned short* __restrict__ Wlo,
    const float* __restrict__ biasAll, float* __restrict__ qkv) {
  const int nt = blockIdx.x;
  const int b  = blockIdx.y;
  const int t  = threadIdx.x;
  const int lane = t & 63;
  const int wid  = t >> 6;
  const int mh = wid >> 2;       // 0,1
  const int nq = wid & 3;        // 0..3
  const int q4 = lane >> 4;
  const int l16 = lane & 15;
  const int n0 = nt * 128;

  __shared__ u16x8 ldsHi[2][128][4];   // 16 KB
  __shared__ u16x8 ldsLo[2][128][4];   // 16 KB

  const int sn  = t & 127;
  const int skb = t >> 7;              // 0..3
  const float* xb = x + (long)b * NC * NSP + n0 + sn;
  const int swz_w = skb ^ (sn & 3);    // write slot

  f32x4 acc[12] = {};
  float xr[8];
#pragma unroll
  for (int j = 0; j < 8; j++) xr[j] = xb[(long)(skb * 8 + j) * NSP];

  for (int s = 0; s < 16; s++) {
    const int buf = s & 1;
    // convert + LDS write
    F8 hi, lo;
#pragma unroll
    for (int j = 0; j < 8; j++) {
      unsigned short h = f2bfu(xr[j]);
      hi.us[j] = h;
      lo.us[j] = f2bfu(xr[j] - bfu2f(h));
    }
    ldsHi[buf][sn][swz_w] = hi.us;
    ldsLo[buf][sn][swz_w] = lo.us;
    __syncthreads();

    // prefetch next step (xr free now; overlaps MFMA phase)
    if (s < 15) {
      const float* src = xb + (long)((s + 1) * 32 + skb * 8) * NSP;
#pragma unroll
      for (int j = 0; j < 8; j++) xr[j] = src[(long)j * NSP];
    }

    const int kb = s * 32 + q4 * 8;
    // B fragments from LDS (swizzled slot)
    F8 bhi[2], blo[2];
#pragma unroll
    for (int ni = 0; ni < 2; ni++) {
      const int nl = nq * 32 + ni * 16 + l16;
      const int slot = q4 ^ (nl & 3);
      bhi[ni].us = ldsHi[buf][nl][slot];
      blo[ni].us = ldsLo[buf][nl][slot];
    }
    // 4 split m-tiles (q or k rows)
#pragma unroll
    for (int i = 0; i < 4; i++) {
      const int mt = mh * 4 + i;
      F8 Ahi, Alo;
      Ahi.us = *(const u16x8*)&Whi[(long)(mt * 16 + l16) * NC + kb];
      Alo.us = *(const u16x8*)&Wlo[(long)(mt * 16 + l16) * NC + kb];
#pragma unroll
      for (int ni = 0; ni < 2; ni++) {
        const int a = i * 2 + ni;
        acc[a] = __builtin_amdgcn_mfma_f32_16x16x32_bf16(Ahi.bf, bhi[ni].bf, acc[a], 0, 0, 0);
        acc[a] = __builtin_amdgcn_mfma_f32_16x16x32_bf16(Ahi.bf, blo[ni].bf, acc[a], 0, 0, 0);
        acc[a] = __builtin_amdgcn_mfma_f32_16x16x32_bf16(Alo.bf, bhi[ni].bf, acc[a], 0, 0, 0);
      }
    }
    // 2 v m-tiles
#pragma unroll
    for (int i = 0; i < 2; i++) {
      const int mt = 8 + mh * 2 + i;
      F8 Ahi;
      Ahi.us = *(const u16x8*)&Whi[(long)(mt * 16 + l16) * NC + kb];
#pragma unroll
      for (int ni = 0; ni < 2; ni++) {
        const int a = 8 + i * 2 + ni;
        acc[a] = __builtin_amdgcn_mfma_f32_16x16x32_bf16(Ahi.bf, bhi[ni].bf, acc[a], 0, 0, 0);
      }
    }
  }

  // epilogue: C/D layout col=lane&15, row=(lane>>4)*4+reg
#pragma unroll
  for (int i = 0; i < 4; i++) {
    const int mt = mh * 4 + i;
#pragma unroll
    for (int ni = 0; ni < 2; ni++) {
      const int n = n0 + nq * 32 + ni * 16 + l16;
#pragma unroll
      for (int r = 0; r < 4; r++) {
        const int mrow = mt * 16 + q4 * 4 + r;
        qkv[(long)(b * NM + mrow) * NSP + n] = acc[i * 2 + ni][r] + biasAll[mrow];
      }
    }
  }
#pragma unroll
  for (int i = 0; i < 2; i++) {
    const int mt = 8 + mh * 2 + i;
#pragma unroll
    for (int ni = 0; ni < 2; ni++) {
      const int n = n0 + nq * 32 + ni * 16 + l16;
#pragma unroll
      for (int r = 0; r < 4; r++) {
        const int mrow = mt * 16 + q4 * 4 + r;
        qkv[(long)(b * NM + mrow) * NSP + n] = acc[8 + i * 2 + ni][r] + biasAll[mrow];
      }
    }
  }
}

// ---------------- K2a: partial logits, fp32. Grid (16 ch, 16 b) ----------------
__global__ __launch_bounds__(256) void k2a_logits(const float* __restrict__ qkv,
                                                  float* __restrict__ part) {
  const int ch = blockIdx.x;   // 0..15, each covers 256 spatial
  const int b  = blockIdx.y;
  const int t  = threadIdx.x;
  __shared__ float ldsQ[64][68];
  __shared__ float ldsKT[64][68];
  const float* Qb = qkv + (long)(b * NM) * NSP;
  const float* Kb = Qb + (long)NCB * NSP;
  const int cc0 = (t >> 4) << 2, dd0 = (t & 15) << 2;
  float acc[4][4] = {};

  for (int s = 0; s < 4; s++) {
    const int n0 = ch * 256 + s * 64;
    __syncthreads();
    for (int i = t; i < 1024; i += 256) {
      int r = i >> 4, c4 = (i & 15) << 2;
      *(f32x4*)&ldsQ[r][c4] = *(const f32x4*)&Qb[(long)r * NSP + n0 + c4];
      f32x4 u = *(const f32x4*)&Kb[(long)r * NSP + n0 + c4];
      ldsKT[c4 + 0][r] = u[0]; ldsKT[c4 + 1][r] = u[1];
      ldsKT[c4 + 2][r] = u[2]; ldsKT[c4 + 3][r] = u[3];
    }
    __syncthreads();
    for (int n = 0; n < 64; n += 4) {
      f32x4 qv[4], kv[4];
#pragma unroll
      for (int i = 0; i < 4; i++) qv[i] = *(const f32x4*)&ldsQ[cc0 + i][n];
#pragma unroll
      for (int p = 0; p < 4; p++) kv[p] = *(const f32x4*)&ldsKT[n + p][dd0];
#pragma unroll
      for (int i = 0; i < 4; i++)
#pragma unroll
        for (int p = 0; p < 4; p++) {
          float qq = qv[i][p];
          acc[i][0] += qq * kv[p][0]; acc[i][1] += qq * kv[p][1];
          acc[i][2] += qq * kv[p][2]; acc[i][3] += qq * kv[p][3];
        }
    }
  }
  float* dst = part + (long)(b * 16 + ch) * 4096;
#pragma unroll
  for (int i = 0; i < 4; i++)
#pragma unroll
    for (int j = 0; j < 4; j++)
      dst[(cc0 + i) * 64 + dd0 + j] = acc[i][j];
}

// ---------------- K2b: reduce 16 partials + softmax, one wave per row ----------------
__global__ __launch_bounds__(64) void k2b_softmax(const float* __restrict__ part,
                                                  float* __restrict__ attn) {
  const int row = blockIdx.x;      // 0..63
  const int b   = blockIdx.y;
  const int d   = threadIdx.x;     // 0..63
  float s = 0.f;
  const float* p = part + (long)b * 16 * 4096 + row * 64 + d;
#pragma unroll
  for (int c = 0; c < 16; c++) s += p[(long)c * 4096];
  // wave softmax
  float mx = s;
#pragma unroll
  for (int o = 32; o; o >>= 1) mx = fmaxf(mx, __shfl_xor(mx, o, 64));
  float e = __expf(s - mx);
  float sum = e;
#pragma unroll
  for (int o = 32; o; o >>= 1) sum += __shfl_xor(sum, o, 64);
  attn[(long)(b * 64 + row) * 64 + d] = e / sum;
}

// ---------------- K2c: M' = gamma * Wo @ attn ----------------
__global__ __launch_bounds__(256) void k2c_mprime(const float* __restrict__ attn,
    const float* __restrict__ wo, const float* __restrict__ gamma,
    float* __restrict__ Mp) {
  const int cb = blockIdx.x;
  const int b  = blockIdx.y;
  const int t  = threadIdx.x;
  __shared__ float ldsW[64][68];
  __shared__ float ldsA[64][68];
  for (int i = t; i < 1024; i += 256) {
    int r = i >> 4, c4 = (i & 15) << 2;
    *(f32x4*)&ldsW[r][c4] = *(const f32x4*)&wo[(long)(cb * 64 + r) * 64 + c4];
    *(f32x4*)&ldsA[r][c4] = *(const f32x4*)&attn[(long)(b * 64 + r) * 64 + c4];
  }
  __syncthreads();
  const int cc0 = (t >> 4) << 2, dd0 = (t & 15) << 2;
  float acc[4][4] = {};
  for (int e = 0; e < 64; e += 4) {
    f32x4 wv4[4], av[4];
#pragma unroll
    for (int i = 0; i < 4; i++) wv4[i] = *(const f32x4*)&ldsW[cc0 + i][e];
#pragma unroll
    for (int p = 0; p < 4; p++) av[p] = *(const f32x4*)&ldsA[e + p][dd0];
#pragma unroll
    for (int i = 0; i < 4; i++)
#pragma unroll
      for (int p = 0; p < 4; p++) {
        float ww = wv4[i][p];
        acc[i][0] += ww * av[p][0]; acc[i][1] += ww * av[p][1];
        acc[i][2] += ww * av[p][2]; acc[i][3] += ww * av[p][3];
      }
  }
  const float g = gamma[0];
  float* dst = Mp + (long)(b * NC + cb * 64) * 64;
#pragma unroll
  for (int i = 0; i < 4; i++)
#pragma unroll
    for (int j = 0; j < 4; j++)
      dst[(cc0 + i) * 64 + dd0 + j] = g * acc[i][j];
}

// ---------------- K3: out = M' @ V + gamma*b_o + x ----------------
__global__ __launch_bounds__(256, 3) void k3_out(const float* __restrict__ qkv,
    const float* __restrict__ Mp, const float* __restrict__ x,
    const float* __restrict__ bo, const float* __restrict__ gamma,
    float* __restrict__ out) {
  const int nt = blockIdx.x;
  const int ct = blockIdx.y;
  const int b  = blockIdx.z;
  const int t  = threadIdx.x;
  const int n0 = nt * 128, c0 = ct * 128;
  __shared__ float ldsM[128][68];
  __shared__ float ldsV[32][128];
  const float* Vb = qkv + (long)(b * NM + 128) * NSP;

  for (int k = 0; k < 8; k++) {
    int idx = k * 256 + t;
    int c = idx >> 4, dv = idx & 15;
    *(f32x4*)&ldsM[c][dv * 4] = *(const f32x4*)&Mp[(long)(b * NC + c0 + c) * 64 + dv * 4];
  }

  const int ci = t >> 4, ni = t & 15;
  f32x4 acc[8][2] = {};

  for (int vh = 0; vh < 2; vh++) {
    __syncthreads();
    for (int k = 0; k < 4; k++) {
      int idx = k * 256 + t;
      int row = idx >> 5, nv = idx & 31;
      *(f32x4*)&ldsV[row][nv * 4] =
          *(const f32x4*)&Vb[(long)(vh * 32 + row) * NSP + n0 + nv * 4];
    }
    __syncthreads();
    for (int dd = 0; dd < 32; dd += 4) {
      const int d = vh * 32 + dd;
      f32x4 mi[8];
#pragma unroll
      for (int i = 0; i < 8; i++) mi[i] = *(const f32x4*)&ldsM[ci + 16 * i][d];
#pragma unroll
      for (int p = 0; p < 4; p++) {
        f32x4 v0 = *(const f32x4*)&ldsV[dd + p][ni * 4];
        f32x4 v1 = *(const f32x4*)&ldsV[dd + p][ni * 4 + 64];
#pragma unroll
        for (int i = 0; i < 8; i++) {
          acc[i][0] += mi[i][p] * v0;
          acc[i][1] += mi[i][p] * v1;
        }
      }
    }
  }

  const float g = gamma[0];
#pragma unroll
  for (int i = 0; i < 8; i++) {
    const int c = c0 + ci + 16 * i;
    const float bb = g * bo[c];
#pragma unroll
    for (int h = 0; h < 2; h++) {
      long off = (long)(b * NC + c) * NSP + n0 + ni * 4 + h * 64;
      f32x4 xr = *(const f32x4*)&x[off];
      f32x4 o = acc[i][h] + xr + bb;
      *(f32x4*)&out[off] = o;
    }
  }
}

extern "C" void kernel_launch(void* const* d_in, const int* in_sizes, int n_in,
                              void* d_out, int out_size, void* d_ws, size_t ws_size,
                              hipStream_t stream) {
  const float* x   = (const float*)d_in[0];
  const float* wq  = (const float*)d_in[1];
  const float* bq  = (const float*)d_in[2];
  const float* wk  = (const float*)d_in[3];
  const float* bk  = (const float*)d_in[4];
  const float* wv  = (const float*)d_in[5];
  const float* bv  = (const float*)d_in[6];
  const float* wo  = (const float*)d_in[7];
  const float* bo  = (const float*)d_in[8];
  const float* gm  = (const float*)d_in[9];
  float* out = (float*)d_out;
  float* ws  = (float*)d_ws;

  // ws carve (floats)
  float* qkv  = ws;                       // 192*4096*16 = 12,582,912
  float* part = ws + 12582912;            // 16*16*4096  = 1,048,576
  float* attn = ws + 13631488;            // 65,536
  float* Mp   = ws + 13697024;            // 524,288
  unsigned short* Whi = (unsigned short*)(ws + 14221312);   // 192*512 u16
  unsigned short* Wlo = (unsigned short*)(ws + 14270464);   // 128*512 u16
  float* biasAll = ws + 14303232;         // 192

  k0_wprep<<<384, 256, 0, stream>>>(wq, wk, wv, bq, bk, bv, Whi, Wlo, biasAll);
  k1_qkv<<<dim3(32, 16), 512, 0, stream>>>(x, Whi, Wlo, biasAll, qkv);
  k2a_logits<<<dim3(16, 16), 256, 0, stream>>>(qkv, part);
  k2b_softmax<<<dim3(64, 16), 64, 0, stream>>>(part, attn);
  k2c_mprime<<<dim3(8, 16), 256, 0, stream>>>(attn, wo, gm, Mp);
  k3_out<<<dim3(32, 4, 16), 256, 0, stream>>>(qkv, Mp, x, bo, gm, out);
}